// Round 9
// baseline (43.941 us; speedup 1.0000x reference)
//
#include <hip/hip_runtime.h>
#include <stdint.h>

#define NW 169   // 13*13 windows

typedef float f32x4 __attribute__((ext_vector_type(4)));  // nontemporal-store-compatible

__device__ __forceinline__ float qw128(float x) {
    // fake_quant(w, 128, 8): clip(round(w*128), -128, 127)/128   (round = half-to-even)
    float r = rintf(x * 128.f);
    r = fminf(fmaxf(r, -128.f), 127.f);
    return r * 0.0078125f;
}
__device__ __forceinline__ float qb16384(float x) {
    // fake_quant(b, 128*128, 32): round(b*16384)/16384 (int32 clamp unreachable here)
    return rintf(x * 16384.f) * 6.103515625e-05f;
}

// ================= K1: prep =================
//   [0, 1024)    : quantize table, CHANNEL-SPLIT: plane0 = bytes 0..15 of each row
//                  (channels 0-15, 4 MB), plane1 = bytes 16..31 (channels 16-31, 4 MB).
//                  1 row (32 floats) per thread.
//   [1024, 3072) : board -> 512-bit ballot bitmaps (4 boards/block), 0.5 MB to ws.
__global__ __launch_bounds__(256)
void prep_kernel(const float* __restrict__ emb, uint8_t* __restrict__ plane0,
                 uint8_t* __restrict__ plane1,
                 const int* __restrict__ board, unsigned long long* __restrict__ bb)
{
    int bid = blockIdx.x, tid = threadIdx.x;
    if (bid < 1024) {
        int row = bid * 256 + tid;                       // 262144 rows
        const float4* in4 = (const float4*)emb + (size_t)row * 8;
        uint32_t w[8];
#pragma unroll
        for (int t = 0; t < 8; ++t) {
            float4 f = in4[t];
            float v[4] = {f.x, f.y, f.z, f.w};
            uint32_t u = 0;
#pragma unroll
            for (int j = 0; j < 4; ++j) {
                float x = fminf(fmaxf(v[j], -1.f), 0.9921875f);
                int r = (int)rintf(x * 128.f) + 128;     // biased [0,255], exact
                u |= ((uint32_t)r & 0xFFu) << (8 * j);
            }
            w[t] = u;
        }
        ((uint4*)plane0)[row] = make_uint4(w[0], w[1], w[2], w[3]);
        ((uint4*)plane1)[row] = make_uint4(w[4], w[5], w[6], w[7]);
        return;
    }
    int wv = tid >> 6, lane = tid & 63;
    int b = (bid - 1024) * 4 + wv;                       // 2048 blocks * 4 = 8192 boards
    const int* bp = board + (size_t)b * 450;
#pragma unroll
    for (int t = 0; t < 8; ++t) {
        int n = t * 64 + lane;
        int cell = (n < 450) ? bp[n] : 0;
        unsigned long long m = __ballot(cell != 0);
        if (lane == 0) bb[(size_t)b * 8 + t] = m;
    }
}

// ================= K2: gather =================
//   [0, 1800)    : zero policy plane (nontemporal, overlaps gather latency)
//   [1800, 5896) : 4096 gather blocks. plane = bid&1  ==> with bid%8 XCD round-robin,
//                  even XCDs only touch plane0 (4 MB, L2-resident), odd only plane1.
//                  1 board-plane per wave: lane = window (3 rounds), 16B row-half/lane.
//                  Channel sums are complete per plane -> final clamp here -> vhalf.
__global__ __launch_bounds__(256)
void gather_kernel(const unsigned long long* __restrict__ bb,
                   const uint8_t* __restrict__ plane0,
                   const uint8_t* __restrict__ plane1,
                   float* __restrict__ vhalf, f32x4* __restrict__ policy)
{
    int bid = blockIdx.x, tid = threadIdx.x;
    if (bid < 1800) {
        int i = bid * 256 + tid;                         // 460800 float4 total
        f32x4 z = {0.f, 0.f, 0.f, 0.f};
        __builtin_nontemporal_store(z, &policy[i]);
        return;
    }
    __shared__ unsigned long long ballots[4][8];         // wave-private rows
    int gb = bid - 1800;
    int p = gb & 1;                                      // == bid&1 (1800 even)
    int wv = tid >> 6, lane = tid & 63;
    int b = (gb >> 1) * 4 + wv;                          // 2048 pairs * 4 waves = 8192
    if (lane < 8) ballots[wv][lane] = bb[(size_t)b * 8 + lane];
    const uint8_t* plane = p ? plane1 : plane0;

    // hash 3 windows per lane (lane = window id within round); dynamic `word`
    // indexes LDS (not registers). Intra-wave LDS RAW ordered by lgkmcnt.
    int off[3];
#pragma unroll
    for (int r = 0; r < 3; ++r) {
        int w = r * 64 + lane;
        int wc = min(w, NW - 1);                         // clamp pad lanes
        int wi = wc / 13, wj = wc - wi * 13;
        int idx = 0;
#pragma unroll
        for (int c = 0; c < 2; ++c) {
#pragma unroll
            for (int i = 0; i < 3; ++i) {
                int s = c * 225 + (wi + i) * 15;         // bit start of row (c, wi+i)
                int word = s >> 6, o = s & 63;
                unsigned long long lo = ballots[wv][word];
                unsigned long long hi = ballots[wv][word + 1];
                // (lo>>o)|(hi<<(64-o)); double-shift avoids UB, 0 at o==0
                unsigned long long bits = (lo >> o) | ((hi << 1) << (63 - o));
                idx |= (int)((bits >> wj) & 7ull) << (9 * c + 3 * i);
            }
        }
        off[r] = idx * 16;                               // byte offset of plane row-half
    }

    // issue all 3 gathers back-to-back
    uint4 d0 = *(const uint4*)(plane + off[0]);
    uint4 d1 = *(const uint4*)(plane + off[1]);
    uint4 d2 = *(const uint4*)(plane + off[2]);
    uint32_t k2m = (128 + lane < NW) ? 0xFFFFFFFFu : 0u; // rounds 0,1 always valid
    d2.x &= k2m; d2.y &= k2m; d2.z &= k2m; d2.w &= k2m;

    // packed-u16 accumulate: byte b of 16 = channel p*16+b; word j holds ch 4j..4j+3
    // lo_j: bytepos 0,2 ; hi_j: bytepos 1,3.  max 169*255 = 43095 < 2^16.
    const uint32_t M = 0x00FF00FFu;
    uint32_t lo0 = (d0.x & M) + (d1.x & M) + (d2.x & M);
    uint32_t hi0 = ((d0.x >> 8) & M) + ((d1.x >> 8) & M) + ((d2.x >> 8) & M);
    uint32_t lo1 = (d0.y & M) + (d1.y & M) + (d2.y & M);
    uint32_t hi1 = ((d0.y >> 8) & M) + ((d1.y >> 8) & M) + ((d2.y >> 8) & M);
    uint32_t lo2 = (d0.z & M) + (d1.z & M) + (d2.z & M);
    uint32_t hi2 = ((d0.z >> 8) & M) + ((d1.z >> 8) & M) + ((d2.z >> 8) & M);
    uint32_t lo3 = (d0.w & M) + (d1.w & M) + (d2.w & M);
    uint32_t hi3 = ((d0.w >> 8) & M) + ((d1.w >> 8) & M) + ((d2.w >> 8) & M);

    // full 64-lane butterfly: all lanes end with the totals
#pragma unroll
    for (int o = 1; o <= 32; o <<= 1) {
        lo0 += __shfl_xor(lo0, o); hi0 += __shfl_xor(hi0, o);
        lo1 += __shfl_xor(lo1, o); hi1 += __shfl_xor(hi1, o);
        lo2 += __shfl_xor(lo2, o); hi2 += __shfl_xor(hi2, o);
        lo3 += __shfl_xor(lo3, o); hi3 += __shfl_xor(hi3, o);
    }

    if (lane < 16) {                                     // channel c = lane of this plane
        int j = lane >> 2, pos = lane & 3;               // ternary select: no reg arrays
        uint32_t wl = (j == 0) ? lo0 : (j == 1) ? lo1 : (j == 2) ? lo2 : lo3;
        uint32_t wh = (j == 0) ? hi0 : (j == 1) ? hi1 : (j == 2) ? hi2 : hi3;
        uint32_t src = (pos & 1) ? wh : wl;
        uint32_t val = (pos >= 2) ? (src >> 16) : (src & 0xFFFFu);
        int s = (int)val - 21632;                        // remove 128*169 bias
        s = min(max(s, -128), 127);                      // clip(v,-1,127/128) exactly
        vhalf[(size_t)b * 32 + p * 16 + lane] = (float)s * 0.0078125f;
    }
}

// ================= K3: MLP =================
// 1024 blocks x 256: 8 boards/block, 2 boards/wave. Reads vhalf (1 MB, L2-hot).
__global__ __launch_bounds__(256)
void mlp_kernel(const float* __restrict__ vhalf,
                const float* __restrict__ w1, const float* __restrict__ b1,
                const float* __restrict__ w2, const float* __restrict__ b2,
                const float* __restrict__ w3, const float* __restrict__ b3,
                float* __restrict__ vout)
{
    __shared__ float w1T[32][32], w2T[32][32], w3T[32][4];   // transposed: [k][j]
    __shared__ float b1q[32], b2q[32], b3q[4];
    __shared__ float vlds[8][32], h1lds[8][32], h2lds[8][32]; // wave-private slots

    int tid = threadIdx.x;
    for (int i = tid; i < 1024; i += 256) {
        int j = i & 31, k = i >> 5;
        w1T[k][j] = qw128(w1[j * 32 + k]);
        w2T[k][j] = qw128(w2[j * 32 + k]);
    }
    if (tid < 96) { int k = tid & 31, j = tid >> 5; w3T[k][j] = qw128(w3[j * 32 + k]); }
    if (tid < 32) { b1q[tid] = qb16384(b1[tid]); b2q[tid] = qb16384(b2[tid]); }
    if (tid < 3)  b3q[tid] = qb16384(b3[tid]);
    __syncthreads();                                     // ONLY block-wide barrier

    int wv = tid >> 6, lane = tid & 63;
    int bbase = blockIdx.x * 8;
    int jj = lane & 31, hf = lane >> 5;

#pragma unroll
    for (int rb = 0; rb < 2; ++rb) {
        int s = wv * 2 + rb;
        int b = bbase + s;
        if (lane < 32) vlds[s][lane] = vhalf[(size_t)b * 32 + lane];

        float t1 = 0.f;
#pragma unroll
        for (int k2 = 0; k2 < 16; ++k2) { int k = hf * 16 + k2; t1 = fmaf(vlds[s][k], w1T[k][jj], t1); }
        t1 += __shfl_xor(t1, 32);
        t1 += b1q[jj];
        t1 = fminf(fmaxf(t1, 0.f), 0.9921875f);
        if (lane < 32) h1lds[s][jj] = t1;

        float t2 = 0.f;
#pragma unroll
        for (int k2 = 0; k2 < 16; ++k2) { int k = hf * 16 + k2; t2 = fmaf(h1lds[s][k], w2T[k][jj], t2); }
        t2 += __shfl_xor(t2, 32);
        t2 += b2q[jj];
        t2 = fminf(fmaxf(t2, 0.f), 0.9921875f);
        if (lane < 32) h2lds[s][jj] = t2;

        float t3 = 0.f;
        if (jj < 3) {
#pragma unroll
            for (int k2 = 0; k2 < 16; ++k2) { int k = hf * 16 + k2; t3 = fmaf(h2lds[s][k], w3T[k][jj], t3); }
        }
        t3 += __shfl_xor(t3, 32);
        if (lane < 3) vout[(size_t)b * 3 + lane] = t3 + b3q[lane];
    }
}

extern "C" void kernel_launch(void* const* d_in, const int* in_sizes, int n_in,
                              void* d_out, int out_size, void* d_ws, size_t ws_size,
                              hipStream_t stream) {
    const int*   board = (const int*)d_in[0];
    const float* emb   = (const float*)d_in[1];
    const float* w1    = (const float*)d_in[2];
    const float* b1    = (const float*)d_in[3];
    const float* w2    = (const float*)d_in[4];
    const float* b2    = (const float*)d_in[5];
    const float* w3    = (const float*)d_in[6];
    const float* b3    = (const float*)d_in[7];
    float* out = (float*)d_out;

    uint8_t* plane0 = (uint8_t*)d_ws;                            // 4 MB
    uint8_t* plane1 = plane0 + (1u << 22);                       // 4 MB
    unsigned long long* bb = (unsigned long long*)(plane0 + (1u << 23));  // 0.5 MB
    float* vhalf = (float*)(plane0 + (9u << 20));                // 1 MB

    // v = out[0 : 8192*3], policy = out[24576 : 24576+1843200]
    prep_kernel  <<<3072, 256, 0, stream>>>(emb, plane0, plane1, board, bb);
    gather_kernel<<<5896, 256, 0, stream>>>(bb, plane0, plane1, vhalf,
                                            (f32x4*)(out + 24576));
    mlp_kernel   <<<1024, 256, 0, stream>>>(vhalf, w1, b1, w2, b2, w3, b3, out);
}

// Round 10
// 38.793 us; speedup vs baseline: 1.1327x; 1.1327x over previous
//
#include <hip/hip_runtime.h>
#include <stdint.h>

#define NW 169   // 13*13 windows

typedef float f32x4 __attribute__((ext_vector_type(4)));  // nontemporal-store-compatible

__device__ __forceinline__ float qw128(float x) {
    // fake_quant(w, 128, 8): clip(round(w*128), -128, 127)/128   (round = half-to-even)
    float r = rintf(x * 128.f);
    r = fminf(fmaxf(r, -128.f), 127.f);
    return r * 0.0078125f;
}
__device__ __forceinline__ float qb16384(float x) {
    // fake_quant(b, 128*128, 32): round(b*16384)/16384 (int32 clamp unreachable here)
    return rintf(x * 16384.f) * 6.103515625e-05f;
}

// ================= K1: prep (heterogeneous 256-thread blocks) =================
//   [0, 2048)    : quantize 2^18 x 32 table -> biased uint8, 32B rows INTACT
//   [2048, 3848) : zero policy plane (nontemporal)
//   [3848, 5896) : board -> 512-bit ballot bitmaps (4 boards/block) -> bb
__global__ __launch_bounds__(256)
void prep_kernel(const float* __restrict__ emb, uint8_t* __restrict__ q,
                 f32x4* __restrict__ policy,
                 const int* __restrict__ board, unsigned long long* __restrict__ bb)
{
    int bid = blockIdx.x, tid = threadIdx.x;
    if (bid >= 3848) {                                   // ballot section
        int wv = tid >> 6, lane = tid & 63;
        int b = (bid - 3848) * 4 + wv;
        const int* bp = board + (size_t)b * 450;
#pragma unroll
        for (int t = 0; t < 8; ++t) {
            int n = t * 64 + lane;
            int cell = (n < 450) ? bp[n] : 0;
            unsigned long long m = __ballot(cell != 0);
            if (lane == 0) bb[(size_t)b * 8 + t] = m;
        }
        return;
    }
    if (bid >= 2048) {                                   // policy zero section
        int i = (bid - 2048) * 256 + tid;                // 460800 float4 total
        f32x4 z = {0.f, 0.f, 0.f, 0.f};
        __builtin_nontemporal_store(z, &policy[i]);
        return;
    }
    int i = bid * 256 + tid;                             // 16 floats per thread
    const float4* in4 = (const float4*)emb + (size_t)i * 4;
    uint32_t words[4];
#pragma unroll
    for (int t = 0; t < 4; ++t) {
        float4 f = in4[t];
        float v[4] = {f.x, f.y, f.z, f.w};
        uint32_t w = 0;
#pragma unroll
        for (int j = 0; j < 4; ++j) {
            float x = fminf(fmaxf(v[j], -1.f), 0.9921875f);
            int r = (int)rintf(x * 128.f) + 128;         // biased [0,255], exact
            w |= ((uint32_t)r & 0xFFu) << (8 * j);
        }
        words[t] = w;
    }
    ((uint4*)q)[i] = make_uint4(words[0], words[1], words[2], words[3]);
}

// one gather pass over a compacted offset list; 2 lanes/window (d1 folded into tab),
// 2 window-rounds per iteration for ILP. Masked tail re-reads lst[cnt-1], zeroed.
__device__ __forceinline__ void gather_pass(const int* lst, int cnt,
        const uint8_t* __restrict__ tab, int lane,
        uint32_t& a0lo, uint32_t& a0hi, uint32_t& a1lo, uint32_t& a1hi,
        uint32_t& a2lo, uint32_t& a2hi, uint32_t& a3lo, uint32_t& a3hi)
{
    const uint32_t M = 0x00FF00FFu;
    int half = lane >> 1;                                // window slot 0..31
    for (int base = 0; base < cnt; base += 64) {
        int i0 = base + half, i1 = i0 + 32;
        int o0 = lst[min(i0, cnt - 1)];
        int o1 = lst[min(i1, cnt - 1)];
        uint4 e0 = *(const uint4*)(tab + o0);
        uint4 e1 = *(const uint4*)(tab + o1);
        uint32_t m0 = (i0 < cnt) ? 0xFFFFFFFFu : 0u;
        uint32_t m1 = (i1 < cnt) ? 0xFFFFFFFFu : 0u;
        uint32_t x;
        x = e0.x & m0; a0lo += x & M; a0hi += (x >> 8) & M;
        x = e1.x & m1; a0lo += x & M; a0hi += (x >> 8) & M;
        x = e0.y & m0; a1lo += x & M; a1hi += (x >> 8) & M;
        x = e1.y & m1; a1lo += x & M; a1hi += (x >> 8) & M;
        x = e0.z & m0; a2lo += x & M; a2hi += (x >> 8) & M;
        x = e1.z & m1; a2lo += x & M; a2hi += (x >> 8) & M;
        x = e0.w & m0; a3lo += x & M; a3hi += (x >> 8) & M;
        x = e1.w & m1; a3lo += x & M; a3hi += (x >> 8) & M;
    }
}

// ================= K2: nnue =================
// 1024 blocks x 256 (exactly 4 blocks/CU co-resident), 8 boards/block, 2/wave.
// Hash from bb; per-wave ballot-compaction into low/high lists (idx*32 < 4MB);
// pass 0 (all waves ~lockstep): low 4MB of table -> L2-resident; pass 1: high 4MB.
__global__ __launch_bounds__(256)
void nnue_kernel(const unsigned long long* __restrict__ bb,
                 const uint8_t* __restrict__ embq,
                 const float* __restrict__ w1, const float* __restrict__ b1,
                 const float* __restrict__ w2, const float* __restrict__ b2,
                 const float* __restrict__ w3, const float* __restrict__ b3,
                 float* __restrict__ vout)
{
    __shared__ float w1T[32][32], w2T[32][32], w3T[32][4];   // transposed: [k][j]
    __shared__ float b1q[32], b2q[32], b3q[4];
    // Wave-private below (slot s = wv*2+rb): intra-wave LDS RAW ordered by lgkmcnt,
    // no block barrier needed after the weight-staging one.
    __shared__ unsigned long long ballots[8][8];
    __shared__ int list0[8][176], list1[8][176];             // compacted byte offsets
    __shared__ float vlds[8][32], h1lds[8][32], h2lds[8][32];

    int tid = threadIdx.x;
    for (int i = tid; i < 1024; i += 256) {
        int j = i & 31, k = i >> 5;
        w1T[k][j] = qw128(w1[j * 32 + k]);
        w2T[k][j] = qw128(w2[j * 32 + k]);
    }
    if (tid < 96) { int k = tid & 31, j = tid >> 5; w3T[k][j] = qw128(w3[j * 32 + k]); }
    if (tid < 32) { b1q[tid] = qb16384(b1[tid]); b2q[tid] = qb16384(b2[tid]); }
    if (tid < 3)  b3q[tid] = qb16384(b3[tid]);
    __syncthreads();                                     // ONLY block-wide barrier

    int wv = tid >> 6, lane = tid & 63;
    int bbase = blockIdx.x * 8;
    int sA = wv * 2, sB = sA + 1;
    int c0A = 0, c1A = 0, c0B = 0, c1B = 0;

    // ---- hash + ballot-compaction for this wave's 2 boards ----
#pragma unroll
    for (int rb = 0; rb < 2; ++rb) {
        int s = sA + rb;
        int b = bbase + s;
        if (lane < 8) ballots[s][lane] = bb[(size_t)b * 8 + lane];
        int cnt0 = 0, cnt1 = 0;
#pragma unroll
        for (int r = 0; r < 3; ++r) {
            int w = r * 64 + lane;
            bool valid = (w < NW);
            int wc = min(w, NW - 1);
            int wi = wc / 13, wj = wc - wi * 13;
            int idx = 0;
#pragma unroll
            for (int c = 0; c < 2; ++c) {
#pragma unroll
                for (int i = 0; i < 3; ++i) {
                    int st = c * 225 + (wi + i) * 15;    // bit start of row (c, wi+i)
                    int word = st >> 6, o = st & 63;
                    unsigned long long lo = ballots[s][word];
                    unsigned long long hi = ballots[s][word + 1];
                    // (lo>>o)|(hi<<(64-o)); double-shift avoids UB, 0 at o==0
                    unsigned long long bits = (lo >> o) | ((hi << 1) << (63 - o));
                    idx |= (int)((bits >> wj) & 7ull) << (9 * c + 3 * i);
                }
            }
            int off = idx << 5;                          // byte offset of 32B row
            bool low = off < (1 << 22);                  // first 4 MB of table
            unsigned long long mlow = __ballot(valid && low);
            unsigned long long mhig = __ballot(valid && !low);
            unsigned long long lt = (1ull << lane) - 1ull;
            if (valid && low)  list0[s][cnt0 + (int)__popcll(mlow & lt)] = off;
            if (valid && !low) list1[s][cnt1 + (int)__popcll(mhig & lt)] = off;
            cnt0 += (int)__popcll(mlow);
            cnt1 += (int)__popcll(mhig);
        }
        if (rb == 0) { c0A = cnt0; c1A = cnt1; } else { c0B = cnt0; c1B = cnt1; }
    }

    int d1 = lane & 1;
    const uint8_t* tab = embq + d1 * 16;                 // this lane's 16B row-half
    int jj = lane & 31, hf = lane >> 5;

    // ================= board A =================
    {
        uint32_t a0lo = 0, a0hi = 0, a1lo = 0, a1hi = 0; // packed u16, +128/window bias
        uint32_t a2lo = 0, a2hi = 0, a3lo = 0, a3hi = 0; // max 169*255 = 43095 < 2^16
        gather_pass(list0[sA], c0A, tab, lane, a0lo, a0hi, a1lo, a1hi, a2lo, a2hi, a3lo, a3hi);
        gather_pass(list1[sA], c1A, tab, lane, a0lo, a0hi, a1lo, a1hi, a2lo, a2hi, a3lo, a3hi);
#pragma unroll
        for (int o = 2; o <= 32; o <<= 1) {              // reduce lanes sharing d1
            a0lo += __shfl_xor(a0lo, o); a0hi += __shfl_xor(a0hi, o);
            a1lo += __shfl_xor(a1lo, o); a1hi += __shfl_xor(a1hi, o);
            a2lo += __shfl_xor(a2lo, o); a2hi += __shfl_xor(a2hi, o);
            a3lo += __shfl_xor(a3lo, o); a3hi += __shfl_xor(a3hi, o);
        }
        if (lane < 2) {                                  // lane == d1: ch [16*d1,16*d1+16)
            uint32_t lo[4] = {a0lo, a1lo, a2lo, a3lo};
            uint32_t hi[4] = {a0hi, a1hi, a2hi, a3hi};
#pragma unroll
            for (int j = 0; j < 4; ++j) {
                int c[4];
                c[0] = (int)(lo[j] & 0xFFFFu) - 21632;   // 128*169 bias
                c[1] = (int)(hi[j] & 0xFFFFu) - 21632;
                c[2] = (int)(lo[j] >> 16)     - 21632;
                c[3] = (int)(hi[j] >> 16)     - 21632;
#pragma unroll
                for (int u = 0; u < 4; ++u) {
                    int cc = min(max(c[u], -128), 127);  // clip(v,-1,127/128) exactly
                    vlds[sA][d1 * 16 + j * 4 + u] = (float)cc * 0.0078125f;
                }
            }
        }
        float t1 = 0.f;
#pragma unroll
        for (int k2 = 0; k2 < 16; ++k2) { int k = hf * 16 + k2; t1 = fmaf(vlds[sA][k], w1T[k][jj], t1); }
        t1 += __shfl_xor(t1, 32);
        t1 += b1q[jj];
        t1 = fminf(fmaxf(t1, 0.f), 0.9921875f);
        if (lane < 32) h1lds[sA][jj] = t1;

        float t2 = 0.f;
#pragma unroll
        for (int k2 = 0; k2 < 16; ++k2) { int k = hf * 16 + k2; t2 = fmaf(h1lds[sA][k], w2T[k][jj], t2); }
        t2 += __shfl_xor(t2, 32);
        t2 += b2q[jj];
        t2 = fminf(fmaxf(t2, 0.f), 0.9921875f);
        if (lane < 32) h2lds[sA][jj] = t2;

        float t3 = 0.f;
        if (jj < 3) {
#pragma unroll
            for (int k2 = 0; k2 < 16; ++k2) { int k = hf * 16 + k2; t3 = fmaf(h2lds[sA][k], w3T[k][jj], t3); }
        }
        t3 += __shfl_xor(t3, 32);
        if (lane < 3) vout[(size_t)(bbase + sA) * 3 + lane] = t3 + b3q[lane];
    }

    // ================= board B =================
    {
        uint32_t a0lo = 0, a0hi = 0, a1lo = 0, a1hi = 0;
        uint32_t a2lo = 0, a2hi = 0, a3lo = 0, a3hi = 0;
        gather_pass(list0[sB], c0B, tab, lane, a0lo, a0hi, a1lo, a1hi, a2lo, a2hi, a3lo, a3hi);
        gather_pass(list1[sB], c1B, tab, lane, a0lo, a0hi, a1lo, a1hi, a2lo, a2hi, a3lo, a3hi);
#pragma unroll
        for (int o = 2; o <= 32; o <<= 1) {
            a0lo += __shfl_xor(a0lo, o); a0hi += __shfl_xor(a0hi, o);
            a1lo += __shfl_xor(a1lo, o); a1hi += __shfl_xor(a1hi, o);
            a2lo += __shfl_xor(a2lo, o); a2hi += __shfl_xor(a2hi, o);
            a3lo += __shfl_xor(a3lo, o); a3hi += __shfl_xor(a3hi, o);
        }
        if (lane < 2) {
            uint32_t lo[4] = {a0lo, a1lo, a2lo, a3lo};
            uint32_t hi[4] = {a0hi, a1hi, a2hi, a3hi};
#pragma unroll
            for (int j = 0; j < 4; ++j) {
                int c[4];
                c[0] = (int)(lo[j] & 0xFFFFu) - 21632;
                c[1] = (int)(hi[j] & 0xFFFFu) - 21632;
                c[2] = (int)(lo[j] >> 16)     - 21632;
                c[3] = (int)(hi[j] >> 16)     - 21632;
#pragma unroll
                for (int u = 0; u < 4; ++u) {
                    int cc = min(max(c[u], -128), 127);
                    vlds[sB][d1 * 16 + j * 4 + u] = (float)cc * 0.0078125f;
                }
            }
        }
        float t1 = 0.f;
#pragma unroll
        for (int k2 = 0; k2 < 16; ++k2) { int k = hf * 16 + k2; t1 = fmaf(vlds[sB][k], w1T[k][jj], t1); }
        t1 += __shfl_xor(t1, 32);
        t1 += b1q[jj];
        t1 = fminf(fmaxf(t1, 0.f), 0.9921875f);
        if (lane < 32) h1lds[sB][jj] = t1;

        float t2 = 0.f;
#pragma unroll
        for (int k2 = 0; k2 < 16; ++k2) { int k = hf * 16 + k2; t2 = fmaf(h1lds[sB][k], w2T[k][jj], t2); }
        t2 += __shfl_xor(t2, 32);
        t2 += b2q[jj];
        t2 = fminf(fmaxf(t2, 0.f), 0.9921875f);
        if (lane < 32) h2lds[sB][jj] = t2;

        float t3 = 0.f;
        if (jj < 3) {
#pragma unroll
            for (int k2 = 0; k2 < 16; ++k2) { int k = hf * 16 + k2; t3 = fmaf(h2lds[sB][k], w3T[k][jj], t3); }
        }
        t3 += __shfl_xor(t3, 32);
        if (lane < 3) vout[(size_t)(bbase + sB) * 3 + lane] = t3 + b3q[lane];
    }
}

extern "C" void kernel_launch(void* const* d_in, const int* in_sizes, int n_in,
                              void* d_out, int out_size, void* d_ws, size_t ws_size,
                              hipStream_t stream) {
    const int*   board = (const int*)d_in[0];
    const float* emb   = (const float*)d_in[1];
    const float* w1    = (const float*)d_in[2];
    const float* b1    = (const float*)d_in[3];
    const float* w2    = (const float*)d_in[4];
    const float* b2    = (const float*)d_in[5];
    const float* w3    = (const float*)d_in[6];
    const float* b3    = (const float*)d_in[7];
    float* out = (float*)d_out;
    uint8_t* embq = (uint8_t*)d_ws;                                  // 2^23 B = 8.4 MB
    unsigned long long* bb = (unsigned long long*)(embq + (1u << 23)); // 0.5 MB

    // v = out[0 : 8192*3], policy = out[24576 : 24576+1843200]
    prep_kernel<<<5896, 256, 0, stream>>>(emb, embq, (f32x4*)(out + 24576), board, bb);
    nnue_kernel<<<1024, 256, 0, stream>>>(bb, embq, w1, b1, w2, b2, w3, b3, out);
}